// Round 1
// baseline (2366.665 us; speedup 1.0000x reference)
//
#include <hip/hip_runtime.h>

#define B 4
#define S 2048
#define D 768
#define H 8
#define DK 96
#define NBH (B*H)

static constexpr float INV_SCALE = 0.10206207261596577f; // 1/sqrt(96)
static constexpr float NEG = -1.0e9f;

// ---------------------------------------------------------------------------
// Kernel 1: Q = x @ Wq^T + bq ; KV = x @ Wv^T + bv   (z dim selects which)
// M = B*S = 8192, N = D = 768, K = D = 768. 64x64 tile, 256 thr, 4x4 micro.
// ---------------------------------------------------------------------------
__global__ __launch_bounds__(256) void in_proj_gemm(
    const float* __restrict__ x,
    const float* __restrict__ Wq, const float* __restrict__ bq,
    const float* __restrict__ Wv, const float* __restrict__ bv,
    float* __restrict__ Qb, float* __restrict__ KVb)
{
    const float* __restrict__ Wm  = blockIdx.z ? Wv : Wq;
    const float* __restrict__ bia = blockIdx.z ? bv : bq;
    float* __restrict__ out       = blockIdx.z ? KVb : Qb;

    const int bn = blockIdx.x * 64;
    const int bm = blockIdx.y * 64;
    const int tid = threadIdx.x;
    const int tx = tid & 15, ty = tid >> 4;

    __shared__ float xs[16][65];
    __shared__ float ws[16][65];

    float acc[4][4] = {};

    for (int k0 = 0; k0 < D; k0 += 16) {
        __syncthreads();
        #pragma unroll
        for (int e = tid; e < 1024; e += 256) {
            int r = e >> 4, c = e & 15;
            xs[c][r] = x [(size_t)(bm + r) * D + k0 + c];
            ws[c][r] = Wm[(size_t)(bn + r) * D + k0 + c];
        }
        __syncthreads();
        #pragma unroll
        for (int kk = 0; kk < 16; ++kk) {
            float a[4], bb[4];
            #pragma unroll
            for (int u = 0; u < 4; ++u) a[u]  = xs[kk][ty * 4 + u];
            #pragma unroll
            for (int v = 0; v < 4; ++v) bb[v] = ws[kk][tx * 4 + v];
            #pragma unroll
            for (int u = 0; u < 4; ++u)
                #pragma unroll
                for (int v = 0; v < 4; ++v)
                    acc[u][v] += a[u] * bb[v];
        }
    }

    #pragma unroll
    for (int u = 0; u < 4; ++u) {
        int row = bm + ty * 4 + u;
        #pragma unroll
        for (int v = 0; v < 4; ++v) {
            int col = bn + tx * 4 + v;
            out[(size_t)row * D + col] = acc[u][v] + bia[col];
        }
    }
}

// ---------------------------------------------------------------------------
// Kernel 2: column softmax stats. For each (b,h,j): m_j = max_i w[i,j],
// s_j = sum_i exp(w[i,j]-m_j) over ALL i (w = -1e9 where pad[i] or j>i).
// Block = one (b,h) x 64-column tile; 4 i-groups x 64 cols = 256 threads.
// ---------------------------------------------------------------------------
__global__ __launch_bounds__(256) void col_stats(
    const float* __restrict__ Qb, const float* __restrict__ KVb,
    const int* __restrict__ amask,
    float* __restrict__ colM, float* __restrict__ colSinv)
{
    const int jt = blockIdx.x, bh = blockIdx.y;
    const int b = bh >> 3, h = bh & 7;
    const int j0 = jt * 64;

    __shared__ float kvs[64][97];
    __shared__ float qs [64][97];
    __shared__ float redM[4][64];
    __shared__ float redS[4][64];
    __shared__ int   pads[64];

    const int tid = threadIdx.x;
    const int col = tid & 63, ig = tid >> 6;
    const int jglob = j0 + col;

    for (int e = tid; e < 64 * DK; e += 256) {
        int r = e / DK, c = e % DK;
        kvs[r][c] = KVb[(size_t)(b * S + j0 + r) * D + h * DK + c];
    }

    float m = NEG, ssum = 0.f;

    for (int it = 0; it < S / 64; ++it) {
        const int i0 = it * 64;
        __syncthreads();
        for (int e = tid; e < 64 * DK; e += 256) {
            int r = e / DK, c = e % DK;
            qs[r][c] = Qb[(size_t)(b * S + i0 + r) * D + h * DK + c];
        }
        if (tid < 64) pads[tid] = amask[b * S + i0 + tid];
        __syncthreads();

        const int ibase = ig * 16;
        float w[16];
        #pragma unroll
        for (int ii = 0; ii < 16; ++ii) w[ii] = 0.f;
        for (int d = 0; d < DK; ++d) {
            float kd = kvs[col][d];
            #pragma unroll
            for (int ii = 0; ii < 16; ++ii) w[ii] += qs[ibase + ii][d] * kd;
        }
        #pragma unroll
        for (int ii = 0; ii < 16; ++ii) {
            int i = i0 + ibase + ii;
            float wv = (pads[ibase + ii] != 0 || jglob > i) ? NEG : w[ii] * INV_SCALE;
            float mn = fmaxf(m, wv);
            ssum = ssum * __expf(m - mn) + __expf(wv - mn);
            m = mn;
        }
    }

    redM[ig][col] = m;
    redS[ig][col] = ssum;
    __syncthreads();
    if (ig == 0) {
        float M = redM[0][col];
        #pragma unroll
        for (int g = 1; g < 4; ++g) M = fmaxf(M, redM[g][col]);
        float Ssum = 0.f;
        #pragma unroll
        for (int g = 0; g < 4; ++g) Ssum += redS[g][col] * __expf(redM[g][col] - M);
        colM[bh * S + jglob]    = M;
        colSinv[bh * S + jglob] = 1.0f / Ssum;
    }
}

// ---------------------------------------------------------------------------
// Kernel 3: out[b,i,h*96+d] = x + sum_j exp(w[i,j]-m_j)/s_j * kv[j,d]
// Block = one (b,h) x 64-row tile, loops over all 32 j-tiles.
// ---------------------------------------------------------------------------
__global__ __launch_bounds__(256) void attn_pv(
    const float* __restrict__ Qb, const float* __restrict__ KVb,
    const int* __restrict__ amask,
    const float* __restrict__ colM, const float* __restrict__ colSinv,
    const float* __restrict__ x, float* __restrict__ out)
{
    const int it = blockIdx.x, bh = blockIdx.y;
    const int b = bh >> 3, h = bh & 7;
    const int i0 = it * 64;

    __shared__ float qs [64][97];
    __shared__ float kvs[64][100];   // stride 100 -> 16B-aligned float4 rows
    __shared__ float ps [64][65];
    __shared__ float cm[64], csv[64];
    __shared__ int   padi[64];

    const int tid = threadIdx.x;

    for (int e = tid; e < 64 * DK; e += 256) {
        int r = e / DK, c = e % DK;
        qs[r][c] = Qb[(size_t)(b * S + i0 + r) * D + h * DK + c];
    }
    if (tid < 64) padi[tid] = amask[b * S + i0 + tid];

    float acc[24];
    #pragma unroll
    for (int u = 0; u < 24; ++u) acc[u] = 0.f;

    const int irow = tid & 63, jset = (tid >> 6) * 16;
    const int r = tid >> 2, dstart = (tid & 3) * 24;

    for (int jt2 = 0; jt2 < S / 64; ++jt2) {
        const int j0 = jt2 * 64;
        __syncthreads();
        for (int e = tid; e < 64 * DK; e += 256) {
            int rr = e / DK, c = e % DK;
            kvs[rr][c] = KVb[(size_t)(b * S + j0 + rr) * D + h * DK + c];
        }
        if (tid < 64) {
            cm [tid] = colM   [bh * S + j0 + tid];
            csv[tid] = colSinv[bh * S + j0 + tid];
        }
        __syncthreads();

        // p tile: each thread 16 (irow, j) pairs
        float w[16];
        #pragma unroll
        for (int jj = 0; jj < 16; ++jj) w[jj] = 0.f;
        for (int d = 0; d < DK; ++d) {
            float qd = qs[irow][d];
            #pragma unroll
            for (int jj = 0; jj < 16; ++jj) w[jj] += qd * kvs[jset + jj][d];
        }
        const int iglob = i0 + irow;
        const int pd = padi[irow];
        #pragma unroll
        for (int jj = 0; jj < 16; ++jj) {
            int j = j0 + jset + jj;
            float wv = (pd != 0 || j > iglob) ? NEG : w[jj] * INV_SCALE;
            ps[irow][jset + jj] = __expf(wv - cm[jset + jj]) * csv[jset + jj];
        }
        __syncthreads();

        // accumulate: thread owns (row r, 24 d-cols)
        #pragma unroll 4
        for (int jj = 0; jj < 64; ++jj) {
            float p = ps[r][jj];
            const float4* kv4 = reinterpret_cast<const float4*>(&kvs[jj][dstart]);
            #pragma unroll
            for (int u = 0; u < 6; ++u) {
                float4 vv = kv4[u];
                acc[u * 4 + 0] += p * vv.x;
                acc[u * 4 + 1] += p * vv.y;
                acc[u * 4 + 2] += p * vv.z;
                acc[u * 4 + 3] += p * vv.w;
            }
        }
    }

    const size_t base = (size_t)(b * S + i0 + r) * D + h * DK + dstart;
    #pragma unroll
    for (int u = 0; u < 24; ++u) out[base + u] = acc[u] + x[base + u];
}

// ---------------------------------------------------------------------------
// Kernel 4: in-place LayerNorm over d_out rows (768), gamma/beta.
// ---------------------------------------------------------------------------
__global__ __launch_bounds__(256) void layer_norm(
    float* __restrict__ out,
    const float* __restrict__ gamma, const float* __restrict__ beta)
{
    const int row = blockIdx.x;
    const int tid = threadIdx.x;
    __shared__ float red[256];

    float* o = out + (size_t)row * D;
    float v[3];
    #pragma unroll
    for (int u = 0; u < 3; ++u) v[u] = o[tid + u * 256];

    red[tid] = v[0] + v[1] + v[2];
    __syncthreads();
    for (int off = 128; off > 0; off >>= 1) {
        if (tid < off) red[tid] += red[tid + off];
        __syncthreads();
    }
    const float mu = red[0] * (1.0f / D);
    __syncthreads();

    float d0 = v[0] - mu, d1 = v[1] - mu, d2 = v[2] - mu;
    red[tid] = d0 * d0 + d1 * d1 + d2 * d2;
    __syncthreads();
    for (int off = 128; off > 0; off >>= 1) {
        if (tid < off) red[tid] += red[tid + off];
        __syncthreads();
    }
    const float var = red[0] * (1.0f / D);
    const float inv = 1.0f / sqrtf(var + 1e-5f);

    #pragma unroll
    for (int u = 0; u < 3; ++u) {
        int c = tid + u * 256;
        o[c] = (v[u] - mu) * inv * gamma[c] + beta[c];
    }
}

// ---------------------------------------------------------------------------
extern "C" void kernel_launch(void* const* d_in, const int* in_sizes, int n_in,
                              void* d_out, int out_size, void* d_ws, size_t ws_size,
                              hipStream_t stream)
{
    const float* x     = (const float*)d_in[0];
    const int*   amask = (const int*)  d_in[1];
    const float* Wq    = (const float*)d_in[2];
    const float* bq    = (const float*)d_in[3];
    const float* Wv    = (const float*)d_in[4];
    const float* bv    = (const float*)d_in[5];
    const float* gamma = (const float*)d_in[6];
    const float* beta  = (const float*)d_in[7];
    float* out = (float*)d_out;

    float* Qb      = (float*)d_ws;
    float* KVb     = Qb  + (size_t)B * S * D;
    float* colM    = KVb + (size_t)B * S * D;
    float* colSinv = colM + (size_t)NBH * S;

    in_proj_gemm<<<dim3(D / 64, (B * S) / 64, 2), 256, 0, stream>>>(
        x, Wq, bq, Wv, bv, Qb, KVb);
    col_stats<<<dim3(S / 64, NBH), 256, 0, stream>>>(
        Qb, KVb, amask, colM, colSinv);
    attn_pv<<<dim3(S / 64, NBH), 256, 0, stream>>>(
        Qb, KVb, amask, colM, colSinv, x, out);
    layer_norm<<<B * S, 256, 0, stream>>>(out, gamma, beta);
}

// Round 2
// 369.481 us; speedup vs baseline: 6.4054x; 6.4054x over previous
//
#include <hip/hip_runtime.h>

#define B 4
#define S 2048
#define D 768
#define H 8
#define DK 96
#define NBH (B*H)
#define SD (B*S*D)

typedef __bf16 bf16x8 __attribute__((ext_vector_type(8)));
typedef float f32x4 __attribute__((ext_vector_type(4)));
typedef unsigned short ushort_t;
typedef __attribute__((ext_vector_type(8))) unsigned short ushort8;
typedef __attribute__((ext_vector_type(4))) unsigned short us4;

static constexpr float INV_SCALE = 0.10206207261596577f; // 1/sqrt(96)
static constexpr float NEG = -1.0e9f;

__device__ __forceinline__ ushort_t f2bf(float f) {
    union { float f; unsigned u; } v; v.f = f;
    unsigned r = v.u + 0x7fffu + ((v.u >> 16) & 1u);
    return (ushort_t)(r >> 16);
}

#define MFMA16(a, b, c) __builtin_amdgcn_mfma_f32_16x16x32_bf16((a), (b), (c), 0, 0, 0)

// ---------------------------------------------------------------------------
// Kernel 0: fp32 -> bf16 conversion of x, W_q, W_v
// ---------------------------------------------------------------------------
__global__ __launch_bounds__(256) void convert_bf16(
    const float* __restrict__ x, const float* __restrict__ wq, const float* __restrict__ wv,
    ushort_t* __restrict__ xb, ushort_t* __restrict__ wqb, ushort_t* __restrict__ wvb)
{
    const int stride = gridDim.x * 256;
    const int idx = blockIdx.x * 256 + threadIdx.x;
    for (int i = idx; i < SD / 4; i += stride) {
        float4 v = ((const float4*)x)[i];
        us4 o; o[0] = f2bf(v.x); o[1] = f2bf(v.y); o[2] = f2bf(v.z); o[3] = f2bf(v.w);
        ((us4*)xb)[i] = o;
    }
    for (int i = idx; i < (D * D) / 4; i += stride) {
        float4 v = ((const float4*)wq)[i];
        us4 o; o[0] = f2bf(v.x); o[1] = f2bf(v.y); o[2] = f2bf(v.z); o[3] = f2bf(v.w);
        ((us4*)wqb)[i] = o;
    }
    for (int i = idx; i < (D * D) / 4; i += stride) {
        float4 v = ((const float4*)wv)[i];
        us4 o; o[0] = f2bf(v.x); o[1] = f2bf(v.y); o[2] = f2bf(v.z); o[3] = f2bf(v.w);
        ((us4*)wvb)[i] = o;
    }
}

// ---------------------------------------------------------------------------
// Kernel 1: MFMA GEMM. Q = bf16(x@Wq^T + bq), KV = bf16(x@Wv^T + bv).
// 128x128 tile, 4 waves (2x2), each wave 64x64 = 4x4 frags of 16x16, BK=32.
// ---------------------------------------------------------------------------
__global__ __launch_bounds__(256) void in_proj_gemm(
    const ushort_t* __restrict__ xb,
    const ushort_t* __restrict__ wqb, const float* __restrict__ bq,
    const ushort_t* __restrict__ wvb, const float* __restrict__ bv,
    ushort_t* __restrict__ Qb, ushort_t* __restrict__ KVb)
{
    const ushort_t* __restrict__ Wm = blockIdx.z ? wvb : wqb;
    const float* __restrict__ bia   = blockIdx.z ? bv : bq;
    ushort_t* __restrict__ outp     = blockIdx.z ? KVb : Qb;

    const int bn = blockIdx.x * 128;
    const int bm = blockIdx.y * 128;
    const int tid = threadIdx.x;
    const int lane = tid & 63;
    const int wid = tid >> 6;
    const int wm = (wid >> 1) * 64, wn = (wid & 1) * 64;
    const int lr = lane & 15, lg = lane >> 4;

    __shared__ __align__(16) ushort_t As[128][40];
    __shared__ __align__(16) ushort_t Bs[128][40];

    f32x4 acc[4][4];
    #pragma unroll
    for (int m = 0; m < 4; ++m)
        #pragma unroll
        for (int n = 0; n < 4; ++n) acc[m][n] = (f32x4){0.f, 0.f, 0.f, 0.f};

    for (int k0 = 0; k0 < D; k0 += 32) {
        __syncthreads();
        #pragma unroll
        for (int c = tid; c < 512; c += 256) {
            int r = c >> 2, c8 = (c & 3) * 8;
            *(ushort8*)&As[r][c8] = *(const ushort8*)&xb[(size_t)(bm + r) * D + k0 + c8];
            *(ushort8*)&Bs[r][c8] = *(const ushort8*)&Wm[(size_t)(bn + r) * D + k0 + c8];
        }
        __syncthreads();
        bf16x8 a[4], bfr[4];
        #pragma unroll
        for (int m = 0; m < 4; ++m) a[m]   = *(const bf16x8*)&As[wm + m * 16 + lr][lg * 8];
        #pragma unroll
        for (int n = 0; n < 4; ++n) bfr[n] = *(const bf16x8*)&Bs[wn + n * 16 + lr][lg * 8];
        #pragma unroll
        for (int m = 0; m < 4; ++m)
            #pragma unroll
            for (int n = 0; n < 4; ++n)
                acc[m][n] = MFMA16(a[m], bfr[n], acc[m][n]);
    }

    #pragma unroll
    for (int m = 0; m < 4; ++m) {
        #pragma unroll
        for (int n = 0; n < 4; ++n) {
            int col = bn + wn + n * 16 + lr;
            float bb = bia[col];
            #pragma unroll
            for (int r = 0; r < 4; ++r) {
                int row = bm + wm + m * 16 + lg * 4 + r;
                outp[(size_t)row * D + col] = f2bf(acc[m][n][r] + bb);
            }
        }
    }
}

// ---------------------------------------------------------------------------
// Kernel 2: column softmax stats via MFMA, causal-skipped (i-tiles >= j-tile).
// Exact numpy semantics: fully-masked column -> m=NEG, s = count(all i)=2048
// (fixup adds j0 skipped causal-masked rows, each contributing exp(0)=1).
// ---------------------------------------------------------------------------
__global__ __launch_bounds__(256) void col_stats(
    const ushort_t* __restrict__ Qb, const ushort_t* __restrict__ KVb,
    const int* __restrict__ amask,
    float* __restrict__ colM, float* __restrict__ colSinv)
{
    const int jt = blockIdx.x, bh = blockIdx.y;
    const int b = bh >> 3, h = bh & 7;
    const int j0 = jt * 64;
    const int tid = threadIdx.x;
    const int lane = tid & 63;
    const int w = tid >> 6;
    const int lr = lane & 15, lg = lane >> 4;

    __shared__ __align__(16) ushort_t ks_[64][104];
    __shared__ __align__(16) ushort_t qs[64][104];
    __shared__ int pads[64];
    __shared__ float redM[4][64];
    __shared__ float redS[4][64];

    for (int c = tid; c < 768; c += 256) {
        int r = c / 12, d8 = (c % 12) * 8;
        *(ushort8*)&ks_[r][d8] = *(const ushort8*)&KVb[(size_t)(b * S + j0 + r) * D + h * DK + d8];
    }

    float mr[4], sr[4];
    #pragma unroll
    for (int jf = 0; jf < 4; ++jf) { mr[jf] = NEG; sr[jf] = 0.f; }

    for (int it = jt; it < S / 64; ++it) {
        const int i0 = it * 64;
        __syncthreads();
        for (int c = tid; c < 768; c += 256) {
            int r = c / 12, d8 = (c % 12) * 8;
            *(ushort8*)&qs[r][d8] = *(const ushort8*)&Qb[(size_t)(b * S + i0 + r) * D + h * DK + d8];
        }
        if (tid < 64) pads[tid] = amask[b * S + i0 + tid];
        __syncthreads();

        f32x4 dacc[4];
        #pragma unroll
        for (int jf = 0; jf < 4; ++jf) dacc[jf] = (f32x4){0.f, 0.f, 0.f, 0.f};
        #pragma unroll
        for (int ks2 = 0; ks2 < 3; ++ks2) {
            bf16x8 afr = *(const bf16x8*)&qs[w * 16 + lr][ks2 * 32 + lg * 8];
            #pragma unroll
            for (int jf = 0; jf < 4; ++jf) {
                bf16x8 bfr = *(const bf16x8*)&ks_[jf * 16 + lr][ks2 * 32 + lg * 8];
                dacc[jf] = MFMA16(afr, bfr, dacc[jf]);
            }
        }

        const int ibl = w * 16 + lg * 4;
        int pd[4];
        #pragma unroll
        for (int r = 0; r < 4; ++r) pd[r] = pads[ibl + r];
        #pragma unroll
        for (int jf = 0; jf < 4; ++jf) {
            const int jg = j0 + jf * 16 + lr;
            float wv[4];
            #pragma unroll
            for (int r = 0; r < 4; ++r) {
                int ig = i0 + ibl + r;
                wv[r] = (pd[r] != 0 || jg > ig) ? NEG : dacc[jf][r] * INV_SCALE;
            }
            float vmax = fmaxf(fmaxf(wv[0], wv[1]), fmaxf(wv[2], wv[3]));
            float mn = fmaxf(mr[jf], vmax);
            sr[jf] = sr[jf] * __expf(mr[jf] - mn)
                   + __expf(wv[0] - mn) + __expf(wv[1] - mn)
                   + __expf(wv[2] - mn) + __expf(wv[3] - mn);
            mr[jf] = mn;
        }
    }

    #pragma unroll
    for (int jf = 0; jf < 4; ++jf) {
        float m2 = mr[jf], s2 = sr[jf];
        #pragma unroll
        for (int off = 16; off < 64; off <<= 1) {
            float mo = __shfl_xor(m2, off);
            float so = __shfl_xor(s2, off);
            float mn = fmaxf(m2, mo);
            s2 = s2 * __expf(m2 - mn) + so * __expf(mo - mn);
            m2 = mn;
        }
        if (lg == 0) { redM[w][jf * 16 + lr] = m2; redS[w][jf * 16 + lr] = s2; }
    }
    __syncthreads();
    if (tid < 64) {
        float M = redM[0][tid], Ssum = redS[0][tid];
        #pragma unroll
        for (int g = 1; g < 4; ++g) {
            float mo = redM[g][tid], so = redS[g][tid];
            float mn = fmaxf(M, mo);
            Ssum = Ssum * __expf(M - mn) + so * __expf(mo - mn);
            M = mn;
        }
        if (M == NEG) Ssum += (float)j0;  // skipped i<j0 rows, all causal-masked
        colM[bh * S + j0 + tid] = M;
        colSinv[bh * S + j0 + tid] = 1.0f / Ssum;
    }
}

// ---------------------------------------------------------------------------
// Kernel 3: PV pass. Recompute QK^T tile (bit-identical to stats pass),
// P = exp(w - m_j)*sinv_j -> bf16 -> LDS -> MFMA with KV^T. Causal-skipped.
// ---------------------------------------------------------------------------
__global__ __launch_bounds__(256) void attn_pv(
    const ushort_t* __restrict__ Qb, const ushort_t* __restrict__ KVb,
    const int* __restrict__ amask,
    const float* __restrict__ colM, const float* __restrict__ colSinv,
    const float* __restrict__ x, float* __restrict__ out)
{
    const int it = blockIdx.x, bh = blockIdx.y;
    const int b = bh >> 3, h = bh & 7;
    const int i0 = it * 64;
    const int tid = threadIdx.x;
    const int lane = tid & 63;
    const int w = tid >> 6;
    const int lr = lane & 15, lg = lane >> 4;

    __shared__ __align__(16) ushort_t qs[64][104];
    __shared__ __align__(16) ushort_t kvs[64][104];
    __shared__ __align__(16) ushort_t kvt[96][72];
    __shared__ __align__(16) ushort_t ps[64][72];
    __shared__ float cm[64], csv[64];
    __shared__ int padi[64];

    for (int c = tid; c < 768; c += 256) {
        int r = c / 12, d8 = (c % 12) * 8;
        *(ushort8*)&qs[r][d8] = *(const ushort8*)&Qb[(size_t)(b * S + i0 + r) * D + h * DK + d8];
    }
    if (tid < 64) padi[tid] = amask[b * S + i0 + tid];

    f32x4 acc[6];
    #pragma unroll
    for (int df = 0; df < 6; ++df) acc[df] = (f32x4){0.f, 0.f, 0.f, 0.f};

    for (int jt2 = 0; jt2 <= it; ++jt2) {
        const int j0 = jt2 * 64;
        __syncthreads();
        for (int c = tid; c < 768; c += 256) {
            int r = c / 12, d8 = (c % 12) * 8;
            ushort8 v = *(const ushort8*)&KVb[(size_t)(b * S + j0 + r) * D + h * DK + d8];
            *(ushort8*)&kvs[r][d8] = v;
            #pragma unroll
            for (int e = 0; e < 8; ++e) kvt[d8 + e][r] = v[e];
        }
        if (tid < 64) {
            cm[tid]  = colM[bh * S + j0 + tid];
            csv[tid] = colSinv[bh * S + j0 + tid];
        }
        __syncthreads();

        // QK^T: wave w computes rows [w*16, w*16+16) x 64 j
        f32x4 dacc[4];
        #pragma unroll
        for (int jf = 0; jf < 4; ++jf) dacc[jf] = (f32x4){0.f, 0.f, 0.f, 0.f};
        #pragma unroll
        for (int ks2 = 0; ks2 < 3; ++ks2) {
            bf16x8 afr = *(const bf16x8*)&qs[w * 16 + lr][ks2 * 32 + lg * 8];
            #pragma unroll
            for (int jf = 0; jf < 4; ++jf) {
                bf16x8 bfr = *(const bf16x8*)&kvs[jf * 16 + lr][ks2 * 32 + lg * 8];
                dacc[jf] = MFMA16(afr, bfr, dacc[jf]);
            }
        }

        // mask + exp + normalize -> bf16 P into LDS
        const int ibl = w * 16 + lg * 4;
        #pragma unroll
        for (int jf = 0; jf < 4; ++jf) {
            const int jl = jf * 16 + lr;
            const int jg = j0 + jl;
            const float cmv = cm[jl], csvv = csv[jl];
            #pragma unroll
            for (int r = 0; r < 4; ++r) {
                int ig = i0 + ibl + r;
                bool msk = (padi[ibl + r] != 0) || (jg > ig);
                float wv = msk ? NEG : dacc[jf][r] * INV_SCALE;
                ps[ibl + r][jl] = f2bf(__expf(wv - cmv) * csvv);
            }
        }
        __syncthreads();

        // PV: out[i][d] += P[i][j] * KV[j][d]
        #pragma unroll
        for (int ks2 = 0; ks2 < 2; ++ks2) {
            bf16x8 afr = *(const bf16x8*)&ps[w * 16 + lr][ks2 * 32 + lg * 8];
            #pragma unroll
            for (int df = 0; df < 6; ++df) {
                bf16x8 bfr = *(const bf16x8*)&kvt[df * 16 + lr][ks2 * 32 + lg * 8];
                acc[df] = MFMA16(afr, bfr, acc[df]);
            }
        }
    }

    #pragma unroll
    for (int df = 0; df < 6; ++df) {
        int d = h * DK + df * 16 + lr;
        #pragma unroll
        for (int r = 0; r < 4; ++r) {
            size_t gi = (size_t)(b * S + i0 + w * 16 + lg * 4 + r) * D + d;
            out[gi] = acc[df][r] + x[gi];
        }
    }
}

// ---------------------------------------------------------------------------
// Kernel 4: in-place LayerNorm over rows of out (768), gamma/beta.
// ---------------------------------------------------------------------------
__global__ __launch_bounds__(256) void layer_norm(
    float* __restrict__ out,
    const float* __restrict__ gamma, const float* __restrict__ beta)
{
    const int row = blockIdx.x;
    const int tid = threadIdx.x;
    __shared__ float red[256];

    float* o = out + (size_t)row * D;
    float v[3];
    #pragma unroll
    for (int u = 0; u < 3; ++u) v[u] = o[tid + u * 256];

    red[tid] = v[0] + v[1] + v[2];
    __syncthreads();
    for (int off = 128; off > 0; off >>= 1) {
        if (tid < off) red[tid] += red[tid + off];
        __syncthreads();
    }
    const float mu = red[0] * (1.0f / D);
    __syncthreads();

    float d0 = v[0] - mu, d1 = v[1] - mu, d2 = v[2] - mu;
    red[tid] = d0 * d0 + d1 * d1 + d2 * d2;
    __syncthreads();
    for (int off = 128; off > 0; off >>= 1) {
        if (tid < off) red[tid] += red[tid + off];
        __syncthreads();
    }
    const float var = red[0] * (1.0f / D);
    const float inv = 1.0f / sqrtf(var + 1e-5f);

    #pragma unroll
    for (int u = 0; u < 3; ++u) {
        int c = tid + u * 256;
        o[c] = (v[u] - mu) * inv * gamma[c] + beta[c];
    }
}

// ---------------------------------------------------------------------------
extern "C" void kernel_launch(void* const* d_in, const int* in_sizes, int n_in,
                              void* d_out, int out_size, void* d_ws, size_t ws_size,
                              hipStream_t stream)
{
    const float* x     = (const float*)d_in[0];
    const int*   amask = (const int*)  d_in[1];
    const float* Wq    = (const float*)d_in[2];
    const float* bq    = (const float*)d_in[3];
    const float* Wv    = (const float*)d_in[4];
    const float* bv    = (const float*)d_in[5];
    const float* gamma = (const float*)d_in[6];
    const float* beta  = (const float*)d_in[7];
    float* out = (float*)d_out;

    ushort_t* xb   = (ushort_t*)d_ws;
    ushort_t* wqb  = xb  + (size_t)SD;
    ushort_t* wvb  = wqb + (size_t)D * D;
    ushort_t* Qb   = wvb + (size_t)D * D;
    ushort_t* KVb  = Qb  + (size_t)SD;
    float* colM    = (float*)(KVb + (size_t)SD);
    float* colSinv = colM + (size_t)NBH * S;

    convert_bf16<<<1024, 256, 0, stream>>>(x, Wq, Wv, xb, wqb, wvb);
    in_proj_gemm<<<dim3(D / 128, (B * S) / 128, 2), 256, 0, stream>>>(
        xb, wqb, bq, wvb, bv, Qb, KVb);
    col_stats<<<dim3(S / 64, NBH), 256, 0, stream>>>(
        Qb, KVb, amask, colM, colSinv);
    attn_pv<<<dim3(S / 64, NBH), 256, 0, stream>>>(
        Qb, KVb, amask, colM, colSinv, x, out);
    layer_norm<<<B * S, 256, 0, stream>>>(out, gamma, beta);
}

// Round 3
// 363.397 us; speedup vs baseline: 6.5126x; 1.0167x over previous
//
#include <hip/hip_runtime.h>

#define B 4
#define S 2048
#define D 768
#define H 8
#define DK 96
#define NBH (B*H)
#define SD (B*S*D)

typedef __bf16 bf16x8 __attribute__((ext_vector_type(8)));
typedef float f32x4 __attribute__((ext_vector_type(4)));
typedef unsigned short ushort_t;
typedef __attribute__((ext_vector_type(8))) unsigned short ushort8;
typedef __attribute__((ext_vector_type(4))) unsigned short us4;

static constexpr float INV_SCALE = 0.10206207261596577f; // 1/sqrt(96)
static constexpr float NEG = -1.0e9f;

__device__ __forceinline__ ushort_t f2bf(float f) {
    union { float f; unsigned u; } v; v.f = f;
    unsigned r = v.u + 0x7fffu + ((v.u >> 16) & 1u);
    return (ushort_t)(r >> 16);
}

#define MFMA16(a, b, c) __builtin_amdgcn_mfma_f32_16x16x32_bf16((a), (b), (c), 0, 0, 0)

// ---------------------------------------------------------------------------
// Kernel 0: fp32 -> bf16 conversion of W_q, W_v only (x converted in GEMM).
// ---------------------------------------------------------------------------
__global__ __launch_bounds__(256) void convert_bf16(
    const float* __restrict__ wq, const float* __restrict__ wv,
    ushort_t* __restrict__ wqb, ushort_t* __restrict__ wvb)
{
    const int stride = gridDim.x * 256;
    const int idx = blockIdx.x * 256 + threadIdx.x;
    for (int i = idx; i < (D * D) / 4; i += stride) {
        float4 v = ((const float4*)wq)[i];
        us4 o; o[0] = f2bf(v.x); o[1] = f2bf(v.y); o[2] = f2bf(v.z); o[3] = f2bf(v.w);
        ((us4*)wqb)[i] = o;
        float4 w = ((const float4*)wv)[i];
        us4 p; p[0] = f2bf(w.x); p[1] = f2bf(w.y); p[2] = f2bf(w.z); p[3] = f2bf(w.w);
        ((us4*)wvb)[i] = p;
    }
}

// ---------------------------------------------------------------------------
// Kernel 1: MFMA GEMM. Q = bf16(x@Wq^T + bq), KV = bf16(x@Wv^T + bv).
// 128x128 tile, 4 waves (2x2), each wave 64x64 = 4x4 frags of 16x16, BK=32.
// For z=1 additionally writes KVt[b][h][d][S] (transposed copy, us4 stores).
// ---------------------------------------------------------------------------
__global__ __launch_bounds__(256) void in_proj_gemm(
    const float* __restrict__ x,
    const ushort_t* __restrict__ wqb, const float* __restrict__ bq,
    const ushort_t* __restrict__ wvb, const float* __restrict__ bv,
    ushort_t* __restrict__ Qb, ushort_t* __restrict__ KVb,
    ushort_t* __restrict__ KVt)
{
    const ushort_t* __restrict__ Wm = blockIdx.z ? wvb : wqb;
    const float* __restrict__ bia   = blockIdx.z ? bv : bq;
    ushort_t* __restrict__ outp     = blockIdx.z ? KVb : Qb;

    const int bn = blockIdx.x * 128;
    const int bm = blockIdx.y * 128;
    const int tid = threadIdx.x;
    const int lane = tid & 63;
    const int wid = tid >> 6;
    const int wm = (wid >> 1) * 64, wn = (wid & 1) * 64;
    const int lr = lane & 15, lg = lane >> 4;

    __shared__ __align__(16) ushort_t As[128][40];
    __shared__ __align__(16) ushort_t Bs[128][40];

    f32x4 acc[4][4];
    #pragma unroll
    for (int m = 0; m < 4; ++m)
        #pragma unroll
        for (int n = 0; n < 4; ++n) acc[m][n] = (f32x4){0.f, 0.f, 0.f, 0.f};

    for (int k0 = 0; k0 < D; k0 += 32) {
        __syncthreads();
        #pragma unroll
        for (int c = tid; c < 512; c += 256) {
            int r = c >> 2, c8 = (c & 3) * 8;
            const float* xp = &x[(size_t)(bm + r) * D + k0 + c8];
            float4 v0 = *(const float4*)xp;
            float4 v1 = *(const float4*)(xp + 4);
            ushort8 o;
            o[0] = f2bf(v0.x); o[1] = f2bf(v0.y); o[2] = f2bf(v0.z); o[3] = f2bf(v0.w);
            o[4] = f2bf(v1.x); o[5] = f2bf(v1.y); o[6] = f2bf(v1.z); o[7] = f2bf(v1.w);
            *(ushort8*)&As[r][c8] = o;
            *(ushort8*)&Bs[r][c8] = *(const ushort8*)&Wm[(size_t)(bn + r) * D + k0 + c8];
        }
        __syncthreads();
        bf16x8 a[4], bfr[4];
        #pragma unroll
        for (int m = 0; m < 4; ++m) a[m]   = *(const bf16x8*)&As[wm + m * 16 + lr][lg * 8];
        #pragma unroll
        for (int n = 0; n < 4; ++n) bfr[n] = *(const bf16x8*)&Bs[wn + n * 16 + lr][lg * 8];
        #pragma unroll
        for (int m = 0; m < 4; ++m)
            #pragma unroll
            for (int n = 0; n < 4; ++n)
                acc[m][n] = MFMA16(a[m], bfr[n], acc[m][n]);
    }

    #pragma unroll
    for (int m = 0; m < 4; ++m) {
        #pragma unroll
        for (int n = 0; n < 4; ++n) {
            int col = bn + wn + n * 16 + lr;
            float bb = bia[col];
            int row0 = bm + wm + m * 16 + lg * 4;
            us4 o;
            #pragma unroll
            for (int r = 0; r < 4; ++r) o[r] = f2bf(acc[m][n][r] + bb);
            #pragma unroll
            for (int r = 0; r < 4; ++r) outp[(size_t)(row0 + r) * D + col] = o[r];
            if (blockIdx.z) {
                int hh = col / DK, dd = col - hh * DK;
                int bb2 = row0 >> 11, ss = row0 & (S - 1);
                *(us4*)&KVt[((size_t)(bb2 * H + hh) * DK + dd) * S + ss] = o;
            }
        }
    }
}

// ---------------------------------------------------------------------------
// Kernel 2: column softmax stats via MFMA, causal-skipped (i-tiles >= j-tile).
// Exact numpy semantics: fully-masked column -> m=NEG, s = count(all i)=2048
// (fixup adds j0 skipped causal-masked rows, each contributing exp(0)=1).
// ---------------------------------------------------------------------------
__global__ __launch_bounds__(256) void col_stats(
    const ushort_t* __restrict__ Qb, const ushort_t* __restrict__ KVb,
    const int* __restrict__ amask,
    float* __restrict__ colM, float* __restrict__ colSinv)
{
    const int jt = blockIdx.x, bh = blockIdx.y;
    const int b = bh >> 3, h = bh & 7;
    const int j0 = jt * 64;
    const int tid = threadIdx.x;
    const int lane = tid & 63;
    const int w = tid >> 6;
    const int lr = lane & 15, lg = lane >> 4;

    __shared__ __align__(16) ushort_t ks_[64][104];
    __shared__ __align__(16) ushort_t qs[64][104];
    __shared__ int pads[64];
    __shared__ float redM[4][64];
    __shared__ float redS[4][64];

    for (int c = tid; c < 768; c += 256) {
        int r = c / 12, d8 = (c % 12) * 8;
        *(ushort8*)&ks_[r][d8] = *(const ushort8*)&KVb[(size_t)(b * S + j0 + r) * D + h * DK + d8];
    }

    float mr[4], sr[4];
    #pragma unroll
    for (int jf = 0; jf < 4; ++jf) { mr[jf] = NEG; sr[jf] = 0.f; }

    for (int it = jt; it < S / 64; ++it) {
        const int i0 = it * 64;
        __syncthreads();
        for (int c = tid; c < 768; c += 256) {
            int r = c / 12, d8 = (c % 12) * 8;
            *(ushort8*)&qs[r][d8] = *(const ushort8*)&Qb[(size_t)(b * S + i0 + r) * D + h * DK + d8];
        }
        if (tid < 64) pads[tid] = amask[b * S + i0 + tid];
        __syncthreads();

        f32x4 dacc[4];
        #pragma unroll
        for (int jf = 0; jf < 4; ++jf) dacc[jf] = (f32x4){0.f, 0.f, 0.f, 0.f};
        #pragma unroll
        for (int ks2 = 0; ks2 < 3; ++ks2) {
            bf16x8 afr = *(const bf16x8*)&qs[w * 16 + lr][ks2 * 32 + lg * 8];
            #pragma unroll
            for (int jf = 0; jf < 4; ++jf) {
                bf16x8 bfr = *(const bf16x8*)&ks_[jf * 16 + lr][ks2 * 32 + lg * 8];
                dacc[jf] = MFMA16(afr, bfr, dacc[jf]);
            }
        }

        const int ibl = w * 16 + lg * 4;
        int pd[4];
        #pragma unroll
        for (int r = 0; r < 4; ++r) pd[r] = pads[ibl + r];
        #pragma unroll
        for (int jf = 0; jf < 4; ++jf) {
            const int jg = j0 + jf * 16 + lr;
            float wv[4];
            #pragma unroll
            for (int r = 0; r < 4; ++r) {
                int ig = i0 + ibl + r;
                wv[r] = (pd[r] != 0 || jg > ig) ? NEG : dacc[jf][r] * INV_SCALE;
            }
            float vmax = fmaxf(fmaxf(wv[0], wv[1]), fmaxf(wv[2], wv[3]));
            float mn = fmaxf(mr[jf], vmax);
            sr[jf] = sr[jf] * __expf(mr[jf] - mn)
                   + __expf(wv[0] - mn) + __expf(wv[1] - mn)
                   + __expf(wv[2] - mn) + __expf(wv[3] - mn);
            mr[jf] = mn;
        }
    }

    #pragma unroll
    for (int jf = 0; jf < 4; ++jf) {
        float m2 = mr[jf], s2 = sr[jf];
        #pragma unroll
        for (int off = 16; off < 64; off <<= 1) {
            float mo = __shfl_xor(m2, off);
            float so = __shfl_xor(s2, off);
            float mn = fmaxf(m2, mo);
            s2 = s2 * __expf(m2 - mn) + so * __expf(mo - mn);
            m2 = mn;
        }
        if (lg == 0) { redM[w][jf * 16 + lr] = m2; redS[w][jf * 16 + lr] = s2; }
    }
    __syncthreads();
    if (tid < 64) {
        float M = redM[0][tid], Ssum = redS[0][tid];
        #pragma unroll
        for (int g = 1; g < 4; ++g) {
            float mo = redM[g][tid], so = redS[g][tid];
            float mn = fmaxf(M, mo);
            Ssum = Ssum * __expf(M - mn) + so * __expf(mo - mn);
            M = mn;
        }
        if (M == NEG) Ssum += (float)j0;  // skipped i<j0 rows, all causal-masked
        colM[bh * S + j0 + tid] = M;
        colSinv[bh * S + j0 + tid] = 1.0f / Ssum;
    }
}

// ---------------------------------------------------------------------------
// Kernel 3: PV pass. Recompute QK^T tile (bit-identical to stats pass),
// P = exp(w - m_j)*sinv_j -> bf16 -> LDS -> MFMA with V^T (loaded from KVt,
// vectorized, no in-kernel transpose). Causal-skipped, heavy-tiles-first.
// ---------------------------------------------------------------------------
__global__ __launch_bounds__(256) void attn_pv(
    const ushort_t* __restrict__ Qb, const ushort_t* __restrict__ KVb,
    const ushort_t* __restrict__ KVt,
    const int* __restrict__ amask,
    const float* __restrict__ colM, const float* __restrict__ colSinv,
    const float* __restrict__ x, float* __restrict__ out)
{
    const int it = (S / 64) - 1 - blockIdx.x;   // heavy blocks launch first
    const int bh = blockIdx.y;
    const int b = bh >> 3, h = bh & 7;
    const int i0 = it * 64;
    const int tid = threadIdx.x;
    const int lane = tid & 63;
    const int w = tid >> 6;
    const int lr = lane & 15, lg = lane >> 4;

    __shared__ __align__(16) ushort_t qs[64][104];
    __shared__ __align__(16) ushort_t kvs[64][104];
    __shared__ __align__(16) ushort_t kvt[96][72];
    __shared__ __align__(16) ushort_t ps[64][72];
    __shared__ float cm[64], csv[64];
    __shared__ int padi[64];

    for (int c = tid; c < 768; c += 256) {
        int r = c / 12, d8 = (c % 12) * 8;
        *(ushort8*)&qs[r][d8] = *(const ushort8*)&Qb[(size_t)(b * S + i0 + r) * D + h * DK + d8];
    }
    if (tid < 64) padi[tid] = amask[b * S + i0 + tid];

    f32x4 acc[6];
    #pragma unroll
    for (int df = 0; df < 6; ++df) acc[df] = (f32x4){0.f, 0.f, 0.f, 0.f};

    for (int jt2 = 0; jt2 <= it; ++jt2) {
        const int j0 = jt2 * 64;
        __syncthreads();
        for (int c = tid; c < 768; c += 256) {
            int r = c / 12, d8 = (c % 12) * 8;
            *(ushort8*)&kvs[r][d8] = *(const ushort8*)&KVb[(size_t)(b * S + j0 + r) * D + h * DK + d8];
        }
        for (int c = tid; c < 768; c += 256) {
            int dd = c >> 3, j8 = (c & 7) * 8;
            *(ushort8*)&kvt[dd][j8] = *(const ushort8*)&KVt[((size_t)(b * H + h) * DK + dd) * S + j0 + j8];
        }
        if (tid < 64) {
            cm[tid]  = colM[bh * S + j0 + tid];
            csv[tid] = colSinv[bh * S + j0 + tid];
        }
        __syncthreads();

        // QK^T: wave w computes rows [w*16, w*16+16) x 64 j
        f32x4 dacc[4];
        #pragma unroll
        for (int jf = 0; jf < 4; ++jf) dacc[jf] = (f32x4){0.f, 0.f, 0.f, 0.f};
        #pragma unroll
        for (int ks2 = 0; ks2 < 3; ++ks2) {
            bf16x8 afr = *(const bf16x8*)&qs[w * 16 + lr][ks2 * 32 + lg * 8];
            #pragma unroll
            for (int jf = 0; jf < 4; ++jf) {
                bf16x8 bfr = *(const bf16x8*)&kvs[jf * 16 + lr][ks2 * 32 + lg * 8];
                dacc[jf] = MFMA16(afr, bfr, dacc[jf]);
            }
        }

        // mask + exp + normalize -> bf16 P into LDS
        const int ibl = w * 16 + lg * 4;
        #pragma unroll
        for (int jf = 0; jf < 4; ++jf) {
            const int jl = jf * 16 + lr;
            const int jg = j0 + jl;
            const float cmv = cm[jl], csvv = csv[jl];
            #pragma unroll
            for (int r = 0; r < 4; ++r) {
                int ig = i0 + ibl + r;
                bool msk = (padi[ibl + r] != 0) || (jg > ig);
                float wv = msk ? NEG : dacc[jf][r] * INV_SCALE;
                ps[ibl + r][jl] = f2bf(__expf(wv - cmv) * csvv);
            }
        }
        __syncthreads();

        // PV: out[i][d] += P[i][j] * V^T[d][j]
        #pragma unroll
        for (int ks2 = 0; ks2 < 2; ++ks2) {
            bf16x8 afr = *(const bf16x8*)&ps[w * 16 + lr][ks2 * 32 + lg * 8];
            #pragma unroll
            for (int df = 0; df < 6; ++df) {
                bf16x8 bfr = *(const bf16x8*)&kvt[df * 16 + lr][ks2 * 32 + lg * 8];
                acc[df] = MFMA16(afr, bfr, acc[df]);
            }
        }
    }

    #pragma unroll
    for (int df = 0; df < 6; ++df) {
        int d = h * DK + df * 16 + lr;
        #pragma unroll
        for (int r = 0; r < 4; ++r) {
            size_t gi = (size_t)(b * S + i0 + w * 16 + lg * 4 + r) * D + d;
            out[gi] = acc[df][r] + x[gi];
        }
    }
}

// ---------------------------------------------------------------------------
// Kernel 4: in-place LayerNorm over rows of out (768), gamma/beta.
// ---------------------------------------------------------------------------
__global__ __launch_bounds__(256) void layer_norm(
    float* __restrict__ out,
    const float* __restrict__ gamma, const float* __restrict__ beta)
{
    const int row = blockIdx.x;
    const int tid = threadIdx.x;
    __shared__ float red[256];

    float* o = out + (size_t)row * D;
    float v[3];
    #pragma unroll
    for (int u = 0; u < 3; ++u) v[u] = o[tid + u * 256];

    red[tid] = v[0] + v[1] + v[2];
    __syncthreads();
    for (int off = 128; off > 0; off >>= 1) {
        if (tid < off) red[tid] += red[tid + off];
        __syncthreads();
    }
    const float mu = red[0] * (1.0f / D);
    __syncthreads();

    float d0 = v[0] - mu, d1 = v[1] - mu, d2 = v[2] - mu;
    red[tid] = d0 * d0 + d1 * d1 + d2 * d2;
    __syncthreads();
    for (int off = 128; off > 0; off >>= 1) {
        if (tid < off) red[tid] += red[tid + off];
        __syncthreads();
    }
    const float var = red[0] * (1.0f / D);
    const float inv = 1.0f / sqrtf(var + 1e-5f);

    #pragma unroll
    for (int u = 0; u < 3; ++u) {
        int c = tid + u * 256;
        o[c] = (v[u] - mu) * inv * gamma[c] + beta[c];
    }
}

// ---------------------------------------------------------------------------
extern "C" void kernel_launch(void* const* d_in, const int* in_sizes, int n_in,
                              void* d_out, int out_size, void* d_ws, size_t ws_size,
                              hipStream_t stream)
{
    const float* x     = (const float*)d_in[0];
    const int*   amask = (const int*)  d_in[1];
    const float* Wq    = (const float*)d_in[2];
    const float* bq    = (const float*)d_in[3];
    const float* Wv    = (const float*)d_in[4];
    const float* bv    = (const float*)d_in[5];
    const float* gamma = (const float*)d_in[6];
    const float* beta  = (const float*)d_in[7];
    float* out = (float*)d_out;

    ushort_t* wqb  = (ushort_t*)d_ws;
    ushort_t* wvb  = wqb + (size_t)D * D;
    ushort_t* Qb   = wvb + (size_t)D * D;
    ushort_t* KVb  = Qb  + (size_t)SD;
    ushort_t* KVt  = KVb + (size_t)SD;
    float* colM    = (float*)(KVt + (size_t)SD);
    float* colSinv = colM + (size_t)NBH * S;

    convert_bf16<<<576, 256, 0, stream>>>(Wq, Wv, wqb, wvb);
    in_proj_gemm<<<dim3(D / 128, (B * S) / 128, 2), 256, 0, stream>>>(
        x, wqb, bq, wvb, bv, Qb, KVb, KVt);
    col_stats<<<dim3(S / 64, NBH), 256, 0, stream>>>(
        Qb, KVb, amask, colM, colSinv);
    attn_pv<<<dim3(S / 64, NBH), 256, 0, stream>>>(
        Qb, KVb, KVt, amask, colM, colSinv, x, out);
    layer_norm<<<B * S, 256, 0, stream>>>(out, gamma, beta);
}

// Round 4
// 218.413 us; speedup vs baseline: 10.8357x; 1.6638x over previous
//
#include <hip/hip_runtime.h>

#define B 4
#define S 2048
#define D 768
#define H 8
#define DK 96
#define NBH (B*H)
#define SD (B*S*D)

typedef __bf16 bf16x8 __attribute__((ext_vector_type(8)));
typedef float f32x4 __attribute__((ext_vector_type(4)));
typedef unsigned short ushort_t;
typedef __attribute__((ext_vector_type(8))) unsigned short ushort8;
typedef __attribute__((ext_vector_type(4))) unsigned short us4;

static constexpr float INV_SCALE = 0.10206207261596577f; // 1/sqrt(96)
static constexpr float NEG = -1.0e9f;

__device__ __forceinline__ ushort_t f2bf(float f) {
    union { float f; unsigned u; } v; v.f = f;
    unsigned r = v.u + 0x7fffu + ((v.u >> 16) & 1u);
    return (ushort_t)(r >> 16);
}

#define MFMA16(a, b, c) __builtin_amdgcn_mfma_f32_16x16x32_bf16((a), (b), (c), 0, 0, 0)

// ---------------------------------------------------------------------------
// Kernel 0: fp32 -> bf16 conversion of W_q, W_v.
// ---------------------------------------------------------------------------
__global__ __launch_bounds__(256) void convert_bf16(
    const float* __restrict__ wq, const float* __restrict__ wv,
    ushort_t* __restrict__ wqb, ushort_t* __restrict__ wvb)
{
    const int stride = gridDim.x * 256;
    const int idx = blockIdx.x * 256 + threadIdx.x;
    for (int i = idx; i < (D * D) / 4; i += stride) {
        float4 v = ((const float4*)wq)[i];
        us4 o; o[0] = f2bf(v.x); o[1] = f2bf(v.y); o[2] = f2bf(v.z); o[3] = f2bf(v.w);
        ((us4*)wqb)[i] = o;
        float4 w = ((const float4*)wv)[i];
        us4 p; p[0] = f2bf(w.x); p[1] = f2bf(w.y); p[2] = f2bf(w.z); p[3] = f2bf(w.w);
        ((us4*)wvb)[i] = p;
    }
}

// ---------------------------------------------------------------------------
// Kernel 1: MFMA GEMM, double-buffered LDS + reg-staged prefetch, 1 sync/step.
// Q = bf16(x@Wq^T + bq), KV = bf16(x@Wv^T + bv); z=1 also writes KVt.
// ---------------------------------------------------------------------------
__global__ __launch_bounds__(256) void in_proj_gemm(
    const float* __restrict__ x,
    const ushort_t* __restrict__ wqb, const float* __restrict__ bq,
    const ushort_t* __restrict__ wvb, const float* __restrict__ bv,
    ushort_t* __restrict__ Qb, ushort_t* __restrict__ KVb,
    ushort_t* __restrict__ KVt)
{
    const ushort_t* __restrict__ Wm = blockIdx.z ? wvb : wqb;
    const float* __restrict__ bia   = blockIdx.z ? bv : bq;
    ushort_t* __restrict__ outp     = blockIdx.z ? KVb : Qb;

    const int bn = blockIdx.x * 128;
    const int bm = blockIdx.y * 128;
    const int tid = threadIdx.x;
    const int lane = tid & 63;
    const int wid = tid >> 6;
    const int wm = (wid >> 1) * 64, wn = (wid & 1) * 64;
    const int lr = lane & 15, lg = lane >> 4;

    __shared__ __align__(16) ushort_t As[2][128][40];
    __shared__ __align__(16) ushort_t Bs[2][128][40];

    // staging: thread handles rows r0 and r0+64, cols c8..c8+7 of the 128x32 tile
    const int r0 = tid >> 2, c8 = (tid & 3) * 8;
    const float*    xg0 = &x [(size_t)(bm + r0) * D + c8];
    const float*    xg1 = xg0 + (size_t)64 * D;
    const ushort_t* wg0 = &Wm[(size_t)(bn + r0) * D + c8];
    const ushort_t* wg1 = wg0 + (size_t)64 * D;

    float4 xv[4];
    ushort8 wv2[2];

    f32x4 acc[4][4];
    #pragma unroll
    for (int m = 0; m < 4; ++m)
        #pragma unroll
        for (int n = 0; n < 4; ++n) acc[m][n] = (f32x4){0.f, 0.f, 0.f, 0.f};

    // prologue: tile 0
    {
        xv[0] = *(const float4*)(xg0);     xv[1] = *(const float4*)(xg0 + 4);
        xv[2] = *(const float4*)(xg1);     xv[3] = *(const float4*)(xg1 + 4);
        wv2[0] = *(const ushort8*)(wg0);   wv2[1] = *(const ushort8*)(wg1);
        ushort8 o0, o1;
        o0[0]=f2bf(xv[0].x); o0[1]=f2bf(xv[0].y); o0[2]=f2bf(xv[0].z); o0[3]=f2bf(xv[0].w);
        o0[4]=f2bf(xv[1].x); o0[5]=f2bf(xv[1].y); o0[6]=f2bf(xv[1].z); o0[7]=f2bf(xv[1].w);
        o1[0]=f2bf(xv[2].x); o1[1]=f2bf(xv[2].y); o1[2]=f2bf(xv[2].z); o1[3]=f2bf(xv[2].w);
        o1[4]=f2bf(xv[3].x); o1[5]=f2bf(xv[3].y); o1[6]=f2bf(xv[3].z); o1[7]=f2bf(xv[3].w);
        *(ushort8*)&As[0][r0][c8] = o0;
        *(ushort8*)&As[0][r0 + 64][c8] = o1;
        *(ushort8*)&Bs[0][r0][c8] = wv2[0];
        *(ushort8*)&Bs[0][r0 + 64][c8] = wv2[1];
    }

    for (int k = 0; k < 24; ++k) {
        __syncthreads();
        const int buf = k & 1;
        if (k < 23) {   // issue loads for tile k+1 (latency hidden under MFMA)
            const int ko = (k + 1) * 32;
            xv[0] = *(const float4*)(xg0 + ko);     xv[1] = *(const float4*)(xg0 + ko + 4);
            xv[2] = *(const float4*)(xg1 + ko);     xv[3] = *(const float4*)(xg1 + ko + 4);
            wv2[0] = *(const ushort8*)(wg0 + ko);   wv2[1] = *(const ushort8*)(wg1 + ko);
        }
        bf16x8 a[4], bfr[4];
        #pragma unroll
        for (int m = 0; m < 4; ++m) a[m]   = *(const bf16x8*)&As[buf][wm + m * 16 + lr][lg * 8];
        #pragma unroll
        for (int n = 0; n < 4; ++n) bfr[n] = *(const bf16x8*)&Bs[buf][wn + n * 16 + lr][lg * 8];
        #pragma unroll
        for (int m = 0; m < 4; ++m)
            #pragma unroll
            for (int n = 0; n < 4; ++n)
                acc[m][n] = MFMA16(a[m], bfr[n], acc[m][n]);
        if (k < 23) {   // commit tile k+1 to the other buffer
            const int nb = (k + 1) & 1;
            ushort8 o0, o1;
            o0[0]=f2bf(xv[0].x); o0[1]=f2bf(xv[0].y); o0[2]=f2bf(xv[0].z); o0[3]=f2bf(xv[0].w);
            o0[4]=f2bf(xv[1].x); o0[5]=f2bf(xv[1].y); o0[6]=f2bf(xv[1].z); o0[7]=f2bf(xv[1].w);
            o1[0]=f2bf(xv[2].x); o1[1]=f2bf(xv[2].y); o1[2]=f2bf(xv[2].z); o1[3]=f2bf(xv[2].w);
            o1[4]=f2bf(xv[3].x); o1[5]=f2bf(xv[3].y); o1[6]=f2bf(xv[3].z); o1[7]=f2bf(xv[3].w);
            *(ushort8*)&As[nb][r0][c8] = o0;
            *(ushort8*)&As[nb][r0 + 64][c8] = o1;
            *(ushort8*)&Bs[nb][r0][c8] = wv2[0];
            *(ushort8*)&Bs[nb][r0 + 64][c8] = wv2[1];
        }
    }

    #pragma unroll
    for (int m = 0; m < 4; ++m) {
        #pragma unroll
        for (int n = 0; n < 4; ++n) {
            int col = bn + wn + n * 16 + lr;
            float bb = bia[col];
            int row0 = bm + wm + m * 16 + lg * 4;
            us4 o;
            #pragma unroll
            for (int r = 0; r < 4; ++r) o[r] = f2bf(acc[m][n][r] + bb);
            #pragma unroll
            for (int r = 0; r < 4; ++r) outp[(size_t)(row0 + r) * D + col] = o[r];
            if (blockIdx.z) {
                int hh = col / DK, dd = col - hh * DK;
                int bb2 = row0 >> 11, ss = row0 & (S - 1);
                *(us4*)&KVt[((size_t)(bb2 * H + hh) * DK + dd) * S + ss] = o;
            }
        }
    }
}

// ---------------------------------------------------------------------------
// Kernel 2: column softmax stats. Wave w owns 16 columns (K-frags in regs);
// online (m,s) is lane-local. Q tiles double-buffered in LDS, reg-prefetched,
// ONE __syncthreads per i-tile.
// ---------------------------------------------------------------------------
__global__ __launch_bounds__(256) void col_stats(
    const ushort_t* __restrict__ Qb, const ushort_t* __restrict__ KVb,
    const int* __restrict__ amask,
    float* __restrict__ colM, float* __restrict__ colSinv)
{
    const int jt = blockIdx.x, bh = blockIdx.y;
    const int b = bh >> 3, h = bh & 7;
    const int j0 = jt * 64;
    const int tid = threadIdx.x;
    const int lane = tid & 63;
    const int w = tid >> 6;
    const int lr = lane & 15, lg = lane >> 4;

    __shared__ __align__(16) ushort_t qs[2][64][104];
    __shared__ int pads[2][64];

    // K fragments in registers: this lane's column j = j0 + w*16 + lr
    bf16x8 kf[3];
    #pragma unroll
    for (int ks2 = 0; ks2 < 3; ++ks2)
        kf[ks2] = *(const bf16x8*)&KVb[(size_t)(b * S + j0 + w * 16 + lr) * D + h * DK + ks2 * 32 + lg * 8];

    // staging address precompute (3 chunks of the 64x96 Q tile per thread)
    int kr[3], kc[3];
    const ushort_t* qg[3];
    #pragma unroll
    for (int k3 = 0; k3 < 3; ++k3) {
        int c = tid + k3 * 256;
        kr[k3] = c / 12; kc[k3] = (c % 12) * 8;
        qg[k3] = &Qb[(size_t)(b * S + j0 + kr[k3]) * D + h * DK + kc[k3]];
    }
    const int* pg = amask + b * S + j0 + (tid < 64 ? tid : 0);

    ushort8 pq[3]; int ppad = 0;
    #pragma unroll
    for (int k3 = 0; k3 < 3; ++k3) { pq[k3] = *(const ushort8*)qg[k3]; qg[k3] += (size_t)64 * D; }
    if (tid < 64) { ppad = *pg; }
    pg += 64;

    float m = NEG, ssum = 0.f;
    const int jg = j0 + w * 16 + lr;
    const int nit = (S / 64) - jt;

    for (int t = 0; t < nit; ++t) {
        const int buf = t & 1;
        const int i0 = j0 + t * 64;
        #pragma unroll
        for (int k3 = 0; k3 < 3; ++k3) *(ushort8*)&qs[buf][kr[k3]][kc[k3]] = pq[k3];
        if (tid < 64) pads[buf][tid] = ppad;
        __syncthreads();
        if (t + 1 < nit) {
            #pragma unroll
            for (int k3 = 0; k3 < 3; ++k3) { pq[k3] = *(const ushort8*)qg[k3]; qg[k3] += (size_t)64 * D; }
            if (tid < 64) { ppad = *pg; }
            pg += 64;
        }

        f32x4 dacc[4];
        #pragma unroll
        for (int f = 0; f < 4; ++f) dacc[f] = (f32x4){0.f, 0.f, 0.f, 0.f};
        #pragma unroll
        for (int ks2 = 0; ks2 < 3; ++ks2) {
            #pragma unroll
            for (int f = 0; f < 4; ++f) {
                bf16x8 afr = *(const bf16x8*)&qs[buf][f * 16 + lr][ks2 * 32 + lg * 8];
                dacc[f] = MFMA16(afr, kf[ks2], dacc[f]);
            }
        }

        // online update, lane-local column jg, 16 i-values
        #pragma unroll
        for (int f = 0; f < 4; ++f) {
            const int ib = f * 16 + lg * 4;
            float wv[4];
            #pragma unroll
            for (int r = 0; r < 4; ++r) {
                int ig = i0 + ib + r;
                wv[r] = (pads[buf][ib + r] != 0 || jg > ig) ? NEG : dacc[f][r] * INV_SCALE;
            }
            float vmax = fmaxf(fmaxf(wv[0], wv[1]), fmaxf(wv[2], wv[3]));
            float mn = fmaxf(m, vmax);
            ssum = ssum * __expf(m - mn)
                 + __expf(wv[0] - mn) + __expf(wv[1] - mn)
                 + __expf(wv[2] - mn) + __expf(wv[3] - mn);
            m = mn;
        }
    }

    // combine the 4 lg-groups (same column, disjoint i-subsets)
    float m2 = m, s2 = ssum;
    #pragma unroll
    for (int off = 16; off < 64; off <<= 1) {
        float mo = __shfl_xor(m2, off);
        float so = __shfl_xor(s2, off);
        float mn = fmaxf(m2, mo);
        s2 = s2 * __expf(m2 - mn) + so * __expf(mo - mn);
        m2 = mn;
    }
    if (lane < 16) {
        if (m2 == NEG) s2 += (float)j0;  // skipped i<j0 rows: all causal-masked, exp(0)=1 each
        colM[bh * S + jg] = m2;
        colSinv[bh * S + jg] = 1.0f / s2;
    }
}

// ---------------------------------------------------------------------------
// Kernel 3: PV pass. Q-frags in regs; KV/V^T/stats reg-prefetched into
// single-buffered LDS (2 syncs/iter); ps is wave-private (no barrier).
// ---------------------------------------------------------------------------
__global__ __launch_bounds__(256, 4) void attn_pv(
    const ushort_t* __restrict__ Qb, const ushort_t* __restrict__ KVb,
    const ushort_t* __restrict__ KVt,
    const int* __restrict__ amask,
    const float* __restrict__ colM, const float* __restrict__ colSinv,
    const float* __restrict__ x, float* __restrict__ out)
{
    const int it = (S / 64) - 1 - blockIdx.x;   // heavy blocks first
    const int bh = blockIdx.y;
    const int b = bh >> 3, h = bh & 7;
    const int i0 = it * 64;
    const int tid = threadIdx.x;
    const int lane = tid & 63;
    const int w = tid >> 6;
    const int lr = lane & 15, lg = lane >> 4;

    __shared__ __align__(16) ushort_t kvs[64][104];
    __shared__ __align__(16) ushort_t kvt[96][72];
    __shared__ __align__(16) ushort_t ps[64][72];
    __shared__ float cm[64], csv[64];
    __shared__ int padi[64];

    // Q fragments in registers (wave w owns rows i0 + w*16 .. +15)
    bf16x8 qf[3];
    #pragma unroll
    for (int ks2 = 0; ks2 < 3; ++ks2)
        qf[ks2] = *(const bf16x8*)&Qb[(size_t)(b * S + i0 + w * 16 + lr) * D + h * DK + ks2 * 32 + lg * 8];

    if (tid < 64) padi[tid] = amask[b * S + i0 + tid];

    // staging addresses (3 chunks each of kvs 64x96 and kvt 96x64)
    int kr[3], kc[3], tr[3], tc[3];
    const ushort_t* kvg[3];
    const ushort_t* ktg[3];
    #pragma unroll
    for (int k3 = 0; k3 < 3; ++k3) {
        int c = tid + k3 * 256;
        kr[k3] = c / 12;  kc[k3] = (c % 12) * 8;
        tr[k3] = c >> 3;  tc[k3] = (c & 7) * 8;
        kvg[k3] = &KVb[(size_t)(b * S + kr[k3]) * D + h * DK + kc[k3]];
        ktg[k3] = &KVt[((size_t)(b * H + h) * DK + tr[k3]) * S + tc[k3]];
    }
    const float* cmg  = colM    + (size_t)bh * S + (tid < 64 ? tid : 0);
    const float* csvg = colSinv + (size_t)bh * S + (tid < 64 ? tid : 0);

    ushort8 pkv[3], pkt[3]; float pcm = 0.f, pcsv = 0.f;
    #pragma unroll
    for (int k3 = 0; k3 < 3; ++k3) {
        pkv[k3] = *(const ushort8*)kvg[k3];  kvg[k3] += (size_t)64 * D;
        pkt[k3] = *(const ushort8*)ktg[k3];  ktg[k3] += 64;
    }
    if (tid < 64) { pcm = *cmg; pcsv = *csvg; }
    cmg += 64; csvg += 64;

    f32x4 acc[6];
    #pragma unroll
    for (int df = 0; df < 6; ++df) acc[df] = (f32x4){0.f, 0.f, 0.f, 0.f};

    for (int jt2 = 0; jt2 <= it; ++jt2) {
        __syncthreads();                       // all waves done reading prev tile
        #pragma unroll
        for (int k3 = 0; k3 < 3; ++k3) {
            *(ushort8*)&kvs[kr[k3]][kc[k3]] = pkv[k3];
            *(ushort8*)&kvt[tr[k3]][tc[k3]] = pkt[k3];
        }
        if (tid < 64) { cm[tid] = pcm; csv[tid] = pcsv; }
        __syncthreads();                       // staging visible
        if (jt2 < it) {                        // issue next-tile loads (hidden under compute)
            #pragma unroll
            for (int k3 = 0; k3 < 3; ++k3) {
                pkv[k3] = *(const ushort8*)kvg[k3];  kvg[k3] += (size_t)64 * D;
                pkt[k3] = *(const ushort8*)ktg[k3];  ktg[k3] += 64;
            }
            if (tid < 64) { pcm = *cmg; pcsv = *csvg; }
            cmg += 64; csvg += 64;
        }

        // QK^T
        f32x4 dacc[4];
        #pragma unroll
        for (int jf = 0; jf < 4; ++jf) dacc[jf] = (f32x4){0.f, 0.f, 0.f, 0.f};
        #pragma unroll
        for (int ks2 = 0; ks2 < 3; ++ks2) {
            #pragma unroll
            for (int jf = 0; jf < 4; ++jf) {
                bf16x8 bfr = *(const bf16x8*)&kvs[jf * 16 + lr][ks2 * 32 + lg * 8];
                dacc[jf] = MFMA16(qf[ks2], bfr, dacc[jf]);
            }
        }

        // mask + exp + normalize -> bf16 P (wave-private rows: no barrier)
        const int ibl = w * 16 + lg * 4;
        const int j0 = jt2 * 64;
        #pragma unroll
        for (int jf = 0; jf < 4; ++jf) {
            const int jl = jf * 16 + lr;
            const int jg = j0 + jl;
            const float cmv = cm[jl], csvv = csv[jl];
            #pragma unroll
            for (int r = 0; r < 4; ++r) {
                int ig = i0 + ibl + r;
                bool msk = (padi[ibl + r] != 0) || (jg > ig);
                float wv = msk ? NEG : dacc[jf][r] * INV_SCALE;
                ps[ibl + r][jl] = f2bf(__expf(wv - cmv) * csvv);
            }
        }

        // PV: out[i][d] += P[i][j] * V^T[d][j]
        #pragma unroll
        for (int ks2 = 0; ks2 < 2; ++ks2) {
            bf16x8 afr = *(const bf16x8*)&ps[w * 16 + lr][ks2 * 32 + lg * 8];
            #pragma unroll
            for (int df = 0; df < 6; ++df) {
                bf16x8 bfr = *(const bf16x8*)&kvt[df * 16 + lr][ks2 * 32 + lg * 8];
                acc[df] = MFMA16(afr, bfr, acc[df]);
            }
        }
    }

    #pragma unroll
    for (int df = 0; df < 6; ++df) {
        int d = h * DK + df * 16 + lr;
        #pragma unroll
        for (int r = 0; r < 4; ++r) {
            size_t gi = (size_t)(b * S + i0 + w * 16 + lg * 4 + r) * D + d;
            out[gi] = acc[df][r] + x[gi];
        }
    }
}

// ---------------------------------------------------------------------------
// Kernel 4: in-place LayerNorm over rows of out (768), gamma/beta.
// ---------------------------------------------------------------------------
__global__ __launch_bounds__(256) void layer_norm(
    float* __restrict__ out,
    const float* __restrict__ gamma, const float* __restrict__ beta)
{
    const int row = blockIdx.x;
    const int tid = threadIdx.x;
    __shared__ float red[256];

    float* o = out + (size_t)row * D;
    float v[3];
    #pragma unroll
    for (int u = 0; u < 3; ++u) v[u] = o[tid + u * 256];

    red[tid] = v[0] + v[1] + v[2];
    __syncthreads();
    for (int off = 128; off > 0; off >>= 1) {
        if (tid < off) red[tid] += red[tid + off];
        __syncthreads();
    }
    const float mu = red[0] * (1.0f / D);
    __syncthreads();

    float d0 = v[0] - mu, d1 = v[1] - mu, d2 = v[2] - mu;
    red[tid] = d0 * d0 + d1 * d1 + d2 * d2;
    __syncthreads();
    for (int off = 128; off > 0; off >>= 1) {
        if (tid < off) red[tid] += red[tid + off];
        __syncthreads();
    }
    const float var = red[0] * (1.0f / D);
    const float inv = 1.0f / sqrtf(var + 1e-5f);

    #pragma unroll
    for (int u = 0; u < 3; ++u) {
        int c = tid + u * 256;
        o[c] = (v[u] - mu) * inv * gamma[c] + beta[c];
    }
}

// ---------------------------------------------------------------------------
extern "C" void kernel_launch(void* const* d_in, const int* in_sizes, int n_in,
                              void* d_out, int out_size, void* d_ws, size_t ws_size,
                              hipStream_t stream)
{
    const float* x     = (const float*)d_in[0];
    const int*   amask = (const int*)  d_in[1];
    const float* Wq    = (const float*)d_in[2];
    const float* bq    = (const float*)d_in[3];
    const float* Wv    = (const float*)d_in[4];
    const float* bv    = (const float*)d_in[5];
    const float* gamma = (const float*)d_in[6];
    const float* beta  = (const float*)d_in[7];
    float* out = (float*)d_out;

    ushort_t* wqb  = (ushort_t*)d_ws;
    ushort_t* wvb  = wqb + (size_t)D * D;
    ushort_t* Qb   = wvb + (size_t)D * D;
    ushort_t* KVb  = Qb  + (size_t)SD;
    ushort_t* KVt  = KVb + (size_t)SD;
    float* colM    = (float*)(KVt + (size_t)SD);
    float* colSinv = colM + (size_t)NBH * S;

    convert_bf16<<<576, 256, 0, stream>>>(Wq, Wv, wqb, wvb);
    in_proj_gemm<<<dim3(D / 128, (B * S) / 128, 2), 256, 0, stream>>>(
        x, wqb, bq, wvb, bv, Qb, KVb, KVt);
    col_stats<<<dim3(S / 64, NBH), 256, 0, stream>>>(
        Qb, KVb, amask, colM, colSinv);
    attn_pv<<<dim3(S / 64, NBH), 256, 0, stream>>>(
        Qb, KVb, KVt, amask, colM, colSinv, x, out);
    layer_norm<<<B * S, 256, 0, stream>>>(out, gamma, beta);
}

// Round 5
// 178.086 us; speedup vs baseline: 13.2894x; 1.2264x over previous
//
#include <hip/hip_runtime.h>

#define B 4
#define S 2048
#define D 768
#define H 8
#define DK 96
#define NBH (B*H)
#define SD (B*S*D)

typedef __bf16 bf16x8 __attribute__((ext_vector_type(8)));
typedef float f32x4 __attribute__((ext_vector_type(4)));
typedef unsigned short ushort_t;
typedef __attribute__((ext_vector_type(8))) unsigned short ushort8;
typedef __attribute__((ext_vector_type(4))) unsigned short us4;

static constexpr float INV_SCALE = 0.10206207261596577f; // 1/sqrt(96)
static constexpr float NEG = -1.0e9f;

__device__ __forceinline__ ushort_t f2bf(float f) {
    union { float f; unsigned u; } v; v.f = f;
    unsigned r = v.u + 0x7fffu + ((v.u >> 16) & 1u);
    return (ushort_t)(r >> 16);
}

// hardware packed f32->bf16 (RNE), 2 elements per instruction
__device__ __forceinline__ unsigned cvt_pk(float a, float b) {
    unsigned d;
    asm("v_cvt_pk_bf16_f32 %0, %1, %2" : "=v"(d) : "v"(a), "v"(b));
    return d;
}
__device__ __forceinline__ ushort8 pack8(const float4& a, const float4& b) {
    union { unsigned u[4]; ushort8 s; } r;
    r.u[0] = cvt_pk(a.x, a.y); r.u[1] = cvt_pk(a.z, a.w);
    r.u[2] = cvt_pk(b.x, b.y); r.u[3] = cvt_pk(b.z, b.w);
    return r.s;
}
__device__ __forceinline__ us4 pack4(const float4& a) {
    union { unsigned u[2]; us4 s; } r;
    r.u[0] = cvt_pk(a.x, a.y); r.u[1] = cvt_pk(a.z, a.w);
    return r.s;
}

#define MFMA16(a, b, c) __builtin_amdgcn_mfma_f32_16x16x32_bf16((a), (b), (c), 0, 0, 0)

// ---------------------------------------------------------------------------
// Kernel 0: fp32 -> bf16 conversion of W_q, W_v.
// ---------------------------------------------------------------------------
__global__ __launch_bounds__(256) void convert_bf16(
    const float* __restrict__ wq, const float* __restrict__ wv,
    ushort_t* __restrict__ wqb, ushort_t* __restrict__ wvb)
{
    const int stride = gridDim.x * 256;
    const int idx = blockIdx.x * 256 + threadIdx.x;
    for (int i = idx; i < (D * D) / 4; i += stride) {
        ((us4*)wqb)[i] = pack4(((const float4*)wq)[i]);
        ((us4*)wvb)[i] = pack4(((const float4*)wv)[i]);
    }
}

// ---------------------------------------------------------------------------
// Kernel 1: MFMA GEMM, double-buffered LDS + reg-staged prefetch, 1 sync/step.
// Q = bf16(x@Wq^T + bq), KV = bf16(x@Wv^T + bv); z=1 also writes KVt.
// ---------------------------------------------------------------------------
__global__ __launch_bounds__(256) void in_proj_gemm(
    const float* __restrict__ x,
    const ushort_t* __restrict__ wqb, const float* __restrict__ bq,
    const ushort_t* __restrict__ wvb, const float* __restrict__ bv,
    ushort_t* __restrict__ Qb, ushort_t* __restrict__ KVb,
    ushort_t* __restrict__ KVt)
{
    const ushort_t* __restrict__ Wm = blockIdx.z ? wvb : wqb;
    const float* __restrict__ bia   = blockIdx.z ? bv : bq;
    ushort_t* __restrict__ outp     = blockIdx.z ? KVb : Qb;

    const int bn = blockIdx.x * 128;
    const int bm = blockIdx.y * 128;
    const int tid = threadIdx.x;
    const int lane = tid & 63;
    const int wid = tid >> 6;
    const int wm = (wid >> 1) * 64, wn = (wid & 1) * 64;
    const int lr = lane & 15, lg = lane >> 4;

    __shared__ __align__(16) ushort_t As[2][128][40];
    __shared__ __align__(16) ushort_t Bs[2][128][40];

    const int r0 = tid >> 2, c8 = (tid & 3) * 8;
    const float*    xg0 = &x [(size_t)(bm + r0) * D + c8];
    const float*    xg1 = xg0 + (size_t)64 * D;
    const ushort_t* wg0 = &Wm[(size_t)(bn + r0) * D + c8];
    const ushort_t* wg1 = wg0 + (size_t)64 * D;

    float4 xv[4];
    ushort8 wv2[2];

    f32x4 acc[4][4];
    #pragma unroll
    for (int m = 0; m < 4; ++m)
        #pragma unroll
        for (int n = 0; n < 4; ++n) acc[m][n] = (f32x4){0.f, 0.f, 0.f, 0.f};

    // prologue: tile 0
    {
        xv[0] = *(const float4*)(xg0);     xv[1] = *(const float4*)(xg0 + 4);
        xv[2] = *(const float4*)(xg1);     xv[3] = *(const float4*)(xg1 + 4);
        wv2[0] = *(const ushort8*)(wg0);   wv2[1] = *(const ushort8*)(wg1);
        *(ushort8*)&As[0][r0][c8]      = pack8(xv[0], xv[1]);
        *(ushort8*)&As[0][r0 + 64][c8] = pack8(xv[2], xv[3]);
        *(ushort8*)&Bs[0][r0][c8]      = wv2[0];
        *(ushort8*)&Bs[0][r0 + 64][c8] = wv2[1];
    }

    for (int k = 0; k < 24; ++k) {
        __syncthreads();
        const int buf = k & 1;
        if (k < 23) {
            const int ko = (k + 1) * 32;
            xv[0] = *(const float4*)(xg0 + ko);     xv[1] = *(const float4*)(xg0 + ko + 4);
            xv[2] = *(const float4*)(xg1 + ko);     xv[3] = *(const float4*)(xg1 + ko + 4);
            wv2[0] = *(const ushort8*)(wg0 + ko);   wv2[1] = *(const ushort8*)(wg1 + ko);
        }
        bf16x8 a[4], bfr[4];
        #pragma unroll
        for (int m = 0; m < 4; ++m) a[m]   = *(const bf16x8*)&As[buf][wm + m * 16 + lr][lg * 8];
        #pragma unroll
        for (int n = 0; n < 4; ++n) bfr[n] = *(const bf16x8*)&Bs[buf][wn + n * 16 + lr][lg * 8];
        #pragma unroll
        for (int m = 0; m < 4; ++m)
            #pragma unroll
            for (int n = 0; n < 4; ++n)
                acc[m][n] = MFMA16(a[m], bfr[n], acc[m][n]);
        if (k < 23) {
            const int nb = (k + 1) & 1;
            *(ushort8*)&As[nb][r0][c8]      = pack8(xv[0], xv[1]);
            *(ushort8*)&As[nb][r0 + 64][c8] = pack8(xv[2], xv[3]);
            *(ushort8*)&Bs[nb][r0][c8]      = wv2[0];
            *(ushort8*)&Bs[nb][r0 + 64][c8] = wv2[1];
        }
    }

    #pragma unroll
    for (int m = 0; m < 4; ++m) {
        #pragma unroll
        for (int n = 0; n < 4; ++n) {
            int col = bn + wn + n * 16 + lr;
            float bb = bia[col];
            int row0 = bm + wm + m * 16 + lg * 4;
            us4 o;
            #pragma unroll
            for (int r = 0; r < 4; ++r) o[r] = f2bf(acc[m][n][r] + bb);
            #pragma unroll
            for (int r = 0; r < 4; ++r) outp[(size_t)(row0 + r) * D + col] = o[r];
            if (blockIdx.z) {
                int hh = col / DK, dd = col - hh * DK;
                int bb2 = row0 >> 11, ss = row0 & (S - 1);
                *(us4*)&KVt[((size_t)(bb2 * H + hh) * DK + dd) * S + ss] = o;
            }
        }
    }
}

// ---------------------------------------------------------------------------
// Kernel 2: column softmax stats. Wave w owns 16 columns (K-frags in regs);
// online (m,s) is lane-local. Q double-buffered in LDS, 1 sync/iter.
// jt swizzled so a CU's 4 co-resident blocks get different triangular depths.
// ---------------------------------------------------------------------------
__global__ __launch_bounds__(256) void col_stats(
    const ushort_t* __restrict__ Qb, const ushort_t* __restrict__ KVb,
    const int* __restrict__ amask,
    float* __restrict__ colM, float* __restrict__ colSinv)
{
    const int bh = blockIdx.y;
    const int jt = (blockIdx.x + 8 * ((bh >> 3) & 3)) & 31;   // balance swizzle
    const int b = bh >> 3, h = bh & 7;
    const int j0 = jt * 64;
    const int tid = threadIdx.x;
    const int lane = tid & 63;
    const int w = tid >> 6;
    const int lr = lane & 15, lg = lane >> 4;

    __shared__ __align__(16) ushort_t qs[2][64][104];
    __shared__ int pads[2][64];

    bf16x8 kf[3];
    #pragma unroll
    for (int ks2 = 0; ks2 < 3; ++ks2)
        kf[ks2] = *(const bf16x8*)&KVb[(size_t)(b * S + j0 + w * 16 + lr) * D + h * DK + ks2 * 32 + lg * 8];

    int kr[3], kc[3];
    const ushort_t* qg[3];
    #pragma unroll
    for (int k3 = 0; k3 < 3; ++k3) {
        int c = tid + k3 * 256;
        kr[k3] = c / 12; kc[k3] = (c % 12) * 8;
        qg[k3] = &Qb[(size_t)(b * S + j0 + kr[k3]) * D + h * DK + kc[k3]];
    }
    const int* pg = amask + b * S + j0 + (tid < 64 ? tid : 0);

    ushort8 pq[3]; int ppad = 0;
    #pragma unroll
    for (int k3 = 0; k3 < 3; ++k3) { pq[k3] = *(const ushort8*)qg[k3]; qg[k3] += (size_t)64 * D; }
    if (tid < 64) { ppad = *pg; }
    pg += 64;

    float m = NEG, ssum = 0.f;
    const int jg = j0 + w * 16 + lr;
    const int nit = (S / 64) - jt;

    for (int t = 0; t < nit; ++t) {
        const int buf = t & 1;
        const int i0 = j0 + t * 64;
        #pragma unroll
        for (int k3 = 0; k3 < 3; ++k3) *(ushort8*)&qs[buf][kr[k3]][kc[k3]] = pq[k3];
        if (tid < 64) pads[buf][tid] = ppad;
        __syncthreads();
        if (t + 1 < nit) {
            #pragma unroll
            for (int k3 = 0; k3 < 3; ++k3) { pq[k3] = *(const ushort8*)qg[k3]; qg[k3] += (size_t)64 * D; }
            if (tid < 64) { ppad = *pg; }
            pg += 64;
        }

        f32x4 dacc[4];
        #pragma unroll
        for (int f = 0; f < 4; ++f) dacc[f] = (f32x4){0.f, 0.f, 0.f, 0.f};
        #pragma unroll
        for (int ks2 = 0; ks2 < 3; ++ks2) {
            #pragma unroll
            for (int f = 0; f < 4; ++f) {
                bf16x8 afr = *(const bf16x8*)&qs[buf][f * 16 + lr][ks2 * 32 + lg * 8];
                dacc[f] = MFMA16(afr, kf[ks2], dacc[f]);
            }
        }

        #pragma unroll
        for (int f = 0; f < 4; ++f) {
            const int ib = f * 16 + lg * 4;
            float wv[4];
            #pragma unroll
            for (int r = 0; r < 4; ++r) {
                int ig = i0 + ib + r;
                wv[r] = (pads[buf][ib + r] != 0 || jg > ig) ? NEG : dacc[f][r] * INV_SCALE;
            }
            float vmax = fmaxf(fmaxf(wv[0], wv[1]), fmaxf(wv[2], wv[3]));
            float mn = fmaxf(m, vmax);
            ssum = ssum * __expf(m - mn)
                 + __expf(wv[0] - mn) + __expf(wv[1] - mn)
                 + __expf(wv[2] - mn) + __expf(wv[3] - mn);
            m = mn;
        }
    }

    float m2 = m, s2 = ssum;
    #pragma unroll
    for (int off = 16; off < 64; off <<= 1) {
        float mo = __shfl_xor(m2, off);
        float so = __shfl_xor(s2, off);
        float mn = fmaxf(m2, mo);
        s2 = s2 * __expf(m2 - mn) + so * __expf(mo - mn);
        m2 = mn;
    }
    if (lane < 16) {
        if (m2 == NEG) s2 += (float)j0;  // skipped i<j0 rows: causal-masked, exp(0)=1 each
        colM[bh * S + jg] = m2;
        colSinv[bh * S + jg] = 1.0f / s2;
    }
}

// ---------------------------------------------------------------------------
// Kernel 3: PV pass. Swapped QK^T (mfma(K,Q)): lane holds fixed i=lr with
// j in runs of 4 -> P packed via v_cvt_pk + ds_write_b64; stats read as
// broadcast b128. it swizzled for per-CU triangular balance.
// ---------------------------------------------------------------------------
__global__ __launch_bounds__(256, 4) void attn_pv(
    const ushort_t* __restrict__ Qb, const ushort_t* __restrict__ KVb,
    const ushort_t* __restrict__ KVt,
    const int* __restrict__ amask,
    const float* __restrict__ colM, const float* __restrict__ colSinv,
    const float* __restrict__ x, float* __restrict__ out)
{
    const int bh = blockIdx.y;
    const int it = (blockIdx.x + 8 * ((bh >> 3) & 3)) & 31;   // balance swizzle
    const int b = bh >> 3, h = bh & 7;
    const int i0 = it * 64;
    const int tid = threadIdx.x;
    const int lane = tid & 63;
    const int w = tid >> 6;
    const int lr = lane & 15, lg = lane >> 4;

    __shared__ __align__(16) ushort_t kvs[64][104];
    __shared__ __align__(16) ushort_t kvt[96][72];
    __shared__ __align__(16) ushort_t ps[64][72];
    __shared__ __align__(16) float cm[64];
    __shared__ __align__(16) float csv[64];
    __shared__ int padi[64];

    bf16x8 qf[3];
    #pragma unroll
    for (int ks2 = 0; ks2 < 3; ++ks2)
        qf[ks2] = *(const bf16x8*)&Qb[(size_t)(b * S + i0 + w * 16 + lr) * D + h * DK + ks2 * 32 + lg * 8];

    if (tid < 64) padi[tid] = amask[b * S + i0 + tid];

    int kr[3], kc[3], tr[3], tc[3];
    const ushort_t* kvg[3];
    const ushort_t* ktg[3];
    #pragma unroll
    for (int k3 = 0; k3 < 3; ++k3) {
        int c = tid + k3 * 256;
        kr[k3] = c / 12;  kc[k3] = (c % 12) * 8;
        tr[k3] = c >> 3;  tc[k3] = (c & 7) * 8;
        kvg[k3] = &KVb[(size_t)(b * S + kr[k3]) * D + h * DK + kc[k3]];
        ktg[k3] = &KVt[((size_t)(b * H + h) * DK + tr[k3]) * S + tc[k3]];
    }
    const float* cmg  = colM    + (size_t)bh * S + (tid < 64 ? tid : 0);
    const float* csvg = colSinv + (size_t)bh * S + (tid < 64 ? tid : 0);

    ushort8 pkv[3], pkt[3]; float pcm = 0.f, pcsv = 0.f;
    #pragma unroll
    for (int k3 = 0; k3 < 3; ++k3) {
        pkv[k3] = *(const ushort8*)kvg[k3];  kvg[k3] += (size_t)64 * D;
        pkt[k3] = *(const ushort8*)ktg[k3];  ktg[k3] += 64;
    }
    if (tid < 64) { pcm = *cmg; pcsv = *csvg; }
    cmg += 64; csvg += 64;

    f32x4 acc[6];
    #pragma unroll
    for (int df = 0; df < 6; ++df) acc[df] = (f32x4){0.f, 0.f, 0.f, 0.f};

    const int my_pad = (int)(amask[b * S + i0 + w * 16 + lr] != 0);
    const int i_g = i0 + w * 16 + lr;

    for (int jt2 = 0; jt2 <= it; ++jt2) {
        const int j0 = jt2 * 64;
        __syncthreads();
        #pragma unroll
        for (int k3 = 0; k3 < 3; ++k3) {
            *(ushort8*)&kvs[kr[k3]][kc[k3]] = pkv[k3];
            *(ushort8*)&kvt[tr[k3]][tc[k3]] = pkt[k3];
        }
        if (tid < 64) { cm[tid] = pcm; csv[tid] = pcsv; }
        __syncthreads();
        if (jt2 < it) {
            #pragma unroll
            for (int k3 = 0; k3 < 3; ++k3) {
                pkv[k3] = *(const ushort8*)kvg[k3];  kvg[k3] += (size_t)64 * D;
                pkt[k3] = *(const ushort8*)ktg[k3];  ktg[k3] += 64;
            }
            if (tid < 64) { pcm = *cmg; pcsv = *csvg; }
            cmg += 64; csvg += 64;
        }

        // swapped QK^T: D[j-local = lg*4+r][i-local = lr]
        f32x4 dacc[4];
        #pragma unroll
        for (int jf = 0; jf < 4; ++jf) dacc[jf] = (f32x4){0.f, 0.f, 0.f, 0.f};
        #pragma unroll
        for (int ks2 = 0; ks2 < 3; ++ks2) {
            #pragma unroll
            for (int jf = 0; jf < 4; ++jf) {
                bf16x8 afr = *(const bf16x8*)&kvs[jf * 16 + lr][ks2 * 32 + lg * 8];
                dacc[jf] = MFMA16(afr, qf[ks2], dacc[jf]);
            }
        }

        // mask + exp + normalize -> packed bf16 P (row chunk, b64 writes)
        #pragma unroll
        for (int jf = 0; jf < 4; ++jf) {
            const int jbase = jf * 16 + lg * 4;
            f32x4 cmv  = *(const f32x4*)&cm[jbase];
            f32x4 csvv = *(const f32x4*)&csv[jbase];
            float pv[4];
            #pragma unroll
            for (int r = 0; r < 4; ++r) {
                int jgl = j0 + jbase + r;
                bool msk = my_pad || (jgl > i_g);
                float wvv = msk ? NEG : dacc[jf][r] * INV_SCALE;
                pv[r] = __expf(wvv - cmv[r]) * csvv[r];
            }
            union { unsigned u[2]; uint2 v; } o;
            o.u[0] = cvt_pk(pv[0], pv[1]);
            o.u[1] = cvt_pk(pv[2], pv[3]);
            *(uint2*)&ps[w * 16 + lr][jbase] = o.v;
        }

        // PV: out[i][d] += P[i][j] * V^T[d][j]   (ps rows wave-private)
        #pragma unroll
        for (int ks2 = 0; ks2 < 2; ++ks2) {
            bf16x8 afr = *(const bf16x8*)&ps[w * 16 + lr][ks2 * 32 + lg * 8];
            #pragma unroll
            for (int df = 0; df < 6; ++df) {
                bf16x8 bfr = *(const bf16x8*)&kvt[df * 16 + lr][ks2 * 32 + lg * 8];
                acc[df] = MFMA16(afr, bfr, acc[df]);
            }
        }
    }

    #pragma unroll
    for (int df = 0; df < 6; ++df) {
        int d = h * DK + df * 16 + lr;
        #pragma unroll
        for (int r = 0; r < 4; ++r) {
            size_t gi = (size_t)(b * S + i0 + w * 16 + lg * 4 + r) * D + d;
            out[gi] = acc[df][r] + x[gi];
        }
    }
}

// ---------------------------------------------------------------------------
// Kernel 4: LayerNorm, one row per wave, shuffle reductions, no barriers.
// ---------------------------------------------------------------------------
__global__ __launch_bounds__(256) void layer_norm(
    float* __restrict__ out,
    const float* __restrict__ gamma, const float* __restrict__ beta)
{
    const int row = blockIdx.x * 4 + (threadIdx.x >> 6);
    const int lane = threadIdx.x & 63;
    float* o = out + (size_t)row * D;

    float4 v[3];
    #pragma unroll
    for (int p = 0; p < 3; ++p) v[p] = *(const float4*)&o[lane * 4 + p * 256];

    float s = 0.f;
    #pragma unroll
    for (int p = 0; p < 3; ++p) s += v[p].x + v[p].y + v[p].z + v[p].w;
    #pragma unroll
    for (int off = 1; off < 64; off <<= 1) s += __shfl_xor(s, off);
    const float mu = s * (1.0f / D);

    float q = 0.f;
    #pragma unroll
    for (int p = 0; p < 3; ++p) {
        float a = v[p].x - mu, bb = v[p].y - mu, c = v[p].z - mu, dd = v[p].w - mu;
        q += a * a + bb * bb + c * c + dd * dd;
    }
    #pragma unroll
    for (int off = 1; off < 64; off <<= 1) q += __shfl_xor(q, off);
    const float inv = 1.0f / sqrtf(q * (1.0f / D) + 1e-5f);

    #pragma unroll
    for (int p = 0; p < 3; ++p) {
        float4 g = *(const float4*)&gamma[lane * 4 + p * 256];
        float4 bt = *(const float4*)&beta[lane * 4 + p * 256];
        float4 r;
        r.x = (v[p].x - mu) * inv * g.x + bt.x;
        r.y = (v[p].y - mu) * inv * g.y + bt.y;
        r.z = (v[p].z - mu) * inv * g.z + bt.z;
        r.w = (v[p].w - mu) * inv * g.w + bt.w;
        *(float4*)&o[lane * 4 + p * 256] = r;
    }
}

// ---------------------------------------------------------------------------
extern "C" void kernel_launch(void* const* d_in, const int* in_sizes, int n_in,
                              void* d_out, int out_size, void* d_ws, size_t ws_size,
                              hipStream_t stream)
{
    const float* x     = (const float*)d_in[0];
    const int*   amask = (const int*)  d_in[1];
    const float* Wq    = (const float*)d_in[2];
    const float* bq    = (const float*)d_in[3];
    const float* Wv    = (const float*)d_in[4];
    const float* bv    = (const float*)d_in[5];
    const float* gamma = (const float*)d_in[6];
    const float* beta  = (const float*)d_in[7];
    float* out = (float*)d_out;

    ushort_t* wqb  = (ushort_t*)d_ws;
    ushort_t* wvb  = wqb + (size_t)D * D;
    ushort_t* Qb   = wvb + (size_t)D * D;
    ushort_t* KVb  = Qb  + (size_t)SD;
    ushort_t* KVt  = KVb + (size_t)SD;
    float* colM    = (float*)(KVt + (size_t)SD);
    float* colSinv = colM + (size_t)NBH * S;

    convert_bf16<<<576, 256, 0, stream>>>(Wq, Wv, wqb, wvb);
    in_proj_gemm<<<dim3(D / 128, (B * S) / 128, 2), 256, 0, stream>>>(
        x, wqb, bq, wvb, bv, Qb, KVb, KVt);
    col_stats<<<dim3(S / 64, NBH), 256, 0, stream>>>(
        Qb, KVb, amask, colM, colSinv);
    attn_pv<<<dim3(S / 64, NBH), 256, 0, stream>>>(
        Qb, KVb, KVt, amask, colM, colSinv, x, out);
    layer_norm<<<(B * S) / 4, 256, 0, stream>>>(out, gamma, beta);
}